// Round 11
// baseline (109.445 us; speedup 1.0000x reference)
//
#include <hip/hip_runtime.h>
#include <math.h>

// B=8, N=1024, D=128.  kv[b,n,512] = [k_mu | v_mu | k_sigma | v_sigma]
// 2-kernel plan (transposed GEMM, 32-i blocks, K in LDS, fused tail):
//  1) prepass: round fp32 -> bf16 into MFMA-fragment order:
//     frag[side][b][tile16][kc][arr][512 ush], chunk = 64 lanes x 8 bf16.
//     side0 = K (cols 0/256), side1 = V (cols 128/384); arr 0=mu 1=sg.
//     Seeds the 8 log-prob slots of out with LPCONST.
//  2) actor: S^T = V.K^T per 32-i block (TWO 16-i MFMA tiles share every
//     V fragment -> halves the dominant V-frag traffic, 266->133 MB; R8/R10
//     evidence says the kernel is L3-BW-bound at ~7 TB/s on those reads).
//     K frags staged in LDS (16 KB) to avoid 64 VGPRs of resident K.
//     Block = 1024 thr (16 waves, each 64 j); grid 256 = 1 block/CU =
//     16 waves/CU (same occupancy as R10). C[row=j][col=i]: lane's col is
//     a fixed i per tile; 4 regs = 4 j's -> geometric j-sum folds
//     in-register; q-group shuffle reduce; cross-wave LDS combine; inline
//     tanh-normal tail for the 32 rows. No cross-block merge.
// NOTE: no __launch_bounds__ min-waves arg (R5: VGPR clamp + 100MB spill);
// (1024) alone caps VGPR at 128 which this kernel fits (~90 live).
// NOTE: no __threadfence / cross-block merge (R9: L2-writeback storms).
// Plain bf16 is accuracy-safe: absmax 4096 identical for fp32 /
// split-bf16 / bf16 runs (accumulation-order noise dominates).

#define NTOK 1024
#define LPCONST 14147.0828114f   // -3072*ln(0.01)

typedef __bf16 bf16x8 __attribute__((ext_vector_type(8)));
typedef float f32x4 __attribute__((ext_vector_type(4)));
#define MFMA(a, b, c) __builtin_amdgcn_mfma_f32_16x16x32_bf16(a, b, c, 0, 0, 0)

__device__ __forceinline__ unsigned short to_bf16(float x) {
    return (unsigned short)((__float_as_uint(x) + 0x8000u) >> 16);
}

template <int CTRL>
__device__ __forceinline__ float dpp_add(float v) {
    int y = __builtin_amdgcn_update_dpp(0, __float_as_int(v), CTRL, 0xf, 0xf, true);
    return v + __int_as_float(y);
}
__device__ __forceinline__ float red16(float v) {
    v = dpp_add<0xB1>(v);    // xor1 within quad
    v = dpp_add<0x4E>(v);    // xor2 within quad
    v = dpp_add<0x141>(v);   // row_half_mirror
    v = dpp_add<0x140>(v);   // row_mirror
    return v;
}

__device__ __forceinline__ float softplusf(float z) {
    return z > 20.f ? z : log1pf(expf(z));
}

// ---------------- prepass ----------------
__global__ __launch_bounds__(256) void prepass_kernel(
    const float* __restrict__ kv, unsigned short* __restrict__ frag,
    float* __restrict__ out)
{
    const int t = blockIdx.x * 256 + threadIdx.x;   // 0..262143
    if (t < 8) out[8 * NTOK * 3 + t] = LPCONST;     // seed log-prob slots

    const int lane = t & 63;
    const int kc   = (t >> 6) & 3;
    const int tile = (t >> 8) & 63;
    const int b    = (t >> 14) & 7;
    const int side = t >> 17;

    const int row = tile * 16 + (lane & 15);
    const int kof = kc * 32 + (lane >> 4) * 8;
    const float* gp = kv + ((size_t)b * NTOK + row) * 512 + side * 128 + kof;
    const float4 m0 = *(const float4*)gp;
    const float4 m1 = *(const float4*)(gp + 4);
    const float4 s0 = *(const float4*)(gp + 256);
    const float4 s1 = *(const float4*)(gp + 260);

    unsigned short* cp = frag + (size_t)side * 2097152 +
                         (size_t)(b * 64 + tile) * 4096 + kc * 1024 + lane * 8;
    ushort4 h0, h1;
    h0.x = to_bf16(m0.x); h0.y = to_bf16(m0.y); h0.z = to_bf16(m0.z); h0.w = to_bf16(m0.w);
    h1.x = to_bf16(m1.x); h1.y = to_bf16(m1.y); h1.z = to_bf16(m1.z); h1.w = to_bf16(m1.w);
    *(ushort4*)(cp + 0) = h0; *(ushort4*)(cp + 4) = h1;       // arr0 mu
    h0.x = to_bf16(s0.x); h0.y = to_bf16(s0.y); h0.z = to_bf16(s0.z); h0.w = to_bf16(s0.w);
    h1.x = to_bf16(s1.x); h1.y = to_bf16(s1.y); h1.z = to_bf16(s1.z); h1.w = to_bf16(s1.w);
    *(ushort4*)(cp + 512) = h0; *(ushort4*)(cp + 516) = h1;   // arr1 sg
}

// ---------------- fused gemm^T + geometry + tail ----------------
__global__ __launch_bounds__(1024) void actor_kernel(
    const unsigned short* __restrict__ frag, const float* __restrict__ pos,
    const float* __restrict__ eps, float* __restrict__ out)
{
    const int t = threadIdx.x;
    const int w = t >> 6;        // wave 0..15 -> j range [w*64, w*64+64)
    const int lane = t & 63;
    const int q = lane >> 4;
    const int r16 = lane & 15;
    const int b    = blockIdx.x & 7;
    const int ithx = blockIdx.x >> 3;   // 0..31 (pair of 16-i tiles)
    const int i0 = ithx * 32;

    const unsigned short* fragK = frag;             // side 0
    const unsigned short* fragV = frag + 2097152;   // side 1
    const float* posb = pos + (size_t)b * NTOK * 3;

    __shared__ unsigned short sK[8192];     // 16 KB: 2 tiles x 4096 ush
    __shared__ float spos[NTOK * 3];        // 12 KB
    __shared__ float wacc[16 * 32 * 6];     // 12 KB
    __shared__ float fin[192];

    // ---- stage K (2 tiles) + positions into LDS (coalesced) ----
    {
        const unsigned short* kg =
            fragK + (size_t)(b * 64 + ithx * 2) * 4096 + t * 8;
        *(ushort4*)&sK[t * 8 + 0] = *(const ushort4*)(kg + 0);
        *(ushort4*)&sK[t * 8 + 4] = *(const ushort4*)(kg + 4);
    }
    if (t < 768) *(float4*)&spos[t * 4] = *(const float4*)&posb[t * 4];
    __syncthreads();

    // lane's i per tile (C column) is fixed
    const float pix0 = spos[(i0 + r16) * 3 + 0];
    const float piy0 = spos[(i0 + r16) * 3 + 1];
    const float piz0 = spos[(i0 + r16) * 3 + 2];
    const float pix1 = spos[(i0 + 16 + r16) * 3 + 0];
    const float piy1 = spos[(i0 + 16 + r16) * 3 + 1];
    const float piz1 = spos[(i0 + 16 + r16) * 3 + 2];

    float am[2][3] = {};   // [tile][c]
    float al[2][3] = {};

    const unsigned short* vbase =
        fragV + (size_t)(b * 64 + w * 4) * 4096 + lane * 8;
    const int klofs = lane * 8;

    #pragma unroll
    for (int jt = 0; jt < 4; ++jt) {
        const unsigned short* vp = vbase + jt * 4096;
        f32x4 accm0 = (f32x4){0.f, 0.f, 0.f, 0.f};
        f32x4 accs0 = (f32x4){0.f, 0.f, 0.f, 0.f};
        f32x4 accm1 = (f32x4){0.f, 0.f, 0.f, 0.f};
        f32x4 accs1 = (f32x4){0.f, 0.f, 0.f, 0.f};
        #pragma unroll
        for (int kc = 0; kc < 4; ++kc) {
            const bf16x8 Vm = *(const bf16x8*)(vp + kc * 1024);
            const bf16x8 Vs = *(const bf16x8*)(vp + kc * 1024 + 512);
            const bf16x8 K0m = *(const bf16x8*)&sK[kc * 1024 + klofs];
            const bf16x8 K0s = *(const bf16x8*)&sK[kc * 1024 + 512 + klofs];
            const bf16x8 K1m = *(const bf16x8*)&sK[4096 + kc * 1024 + klofs];
            const bf16x8 K1s = *(const bf16x8*)&sK[4096 + kc * 1024 + 512 + klofs];
            accm0 = MFMA(Vm, K0m, accm0);   // C[row=j][col=i], tile 0
            accs0 = MFMA(Vs, K0s, accs0);
            accm1 = MFMA(Vm, K1m, accm1);   // tile 1 shares the V frags
            accs1 = MFMA(Vs, K1s, accs1);
        }
        // ---- fold this tile's 4 j's (rows q*4+reg) into per-i sums ----
        const int jbase = (w * 4 + jt) * 16 + q * 4;
        #pragma unroll
        for (int reg = 0; reg < 4; ++reg) {
            const float* pj = &spos[(jbase + reg) * 3];  // LDS broadcast
            // tile 0
            {
                const float dx = pix0 - pj[0];
                const float dy = piy0 - pj[1];
                const float dz = piz0 - pj[2];
                const float d2 = dx * dx + dy * dy + dz * dz;
                const float inv = d2 > 0.f ? rsqrtf(d2) : 0.f;
                const float wm = accm0[reg] * inv;
                const float ws = accs0[reg] * inv;
                am[0][0] = fmaf(dx, wm, am[0][0]);
                am[0][1] = fmaf(dy, wm, am[0][1]);
                am[0][2] = fmaf(dz, wm, am[0][2]);
                al[0][0] = fmaf(dx, ws, al[0][0]);
                al[0][1] = fmaf(dy, ws, al[0][1]);
                al[0][2] = fmaf(dz, ws, al[0][2]);
            }
            // tile 1
            {
                const float dx = pix1 - pj[0];
                const float dy = piy1 - pj[1];
                const float dz = piz1 - pj[2];
                const float d2 = dx * dx + dy * dy + dz * dz;
                const float inv = d2 > 0.f ? rsqrtf(d2) : 0.f;
                const float wm = accm1[reg] * inv;
                const float ws = accs1[reg] * inv;
                am[1][0] = fmaf(dx, wm, am[1][0]);
                am[1][1] = fmaf(dy, wm, am[1][1]);
                am[1][2] = fmaf(dz, wm, am[1][2]);
                al[1][0] = fmaf(dx, ws, al[1][0]);
                al[1][1] = fmaf(dy, ws, al[1][1]);
                al[1][2] = fmaf(dz, ws, al[1][2]);
            }
        }
    }

    // ---- reduce over the 4 q-groups (lanes r16, +16, +32, +48) ----
    #pragma unroll
    for (int tile = 0; tile < 2; ++tile)
        #pragma unroll
        for (int c = 0; c < 3; ++c) {
            float vm = am[tile][c], vl = al[tile][c];
            vm += __shfl_xor(vm, 16, 64); vm += __shfl_xor(vm, 32, 64);
            vl += __shfl_xor(vl, 16, 64); vl += __shfl_xor(vl, 32, 64);
            am[tile][c] = vm; al[tile][c] = vl;
        }

    // ---- cross-wave combine via LDS ----
    if (lane < 16) {
        #pragma unroll
        for (int tile = 0; tile < 2; ++tile) {
            float* p = wacc + (w * 32 + tile * 16 + r16) * 6;
            p[0] = am[tile][0]; p[1] = am[tile][1]; p[2] = am[tile][2];
            p[3] = al[tile][0]; p[4] = al[tile][1]; p[5] = al[tile][2];
        }
    }
    __syncthreads();
    if (t < 192) {
        float v = 0.f;
        #pragma unroll
        for (int ww = 0; ww < 16; ++ww) v += wacc[ww * 192 + t];
        fin[t] = v;
    }
    __syncthreads();

    // ---- inline tanh-normal tail for the 32 rows ----
    if (t < 32) {
        const int gi = b * NTOK + i0 + t;
        const float* v = fin + t * 6;
        float lp = 0.f;
        #pragma unroll
        for (int c = 0; c < 3; ++c) {
            const float als = fminf(fmaxf(v[3 + c], -20.f), 2.f);
            const float sd = expf(als);
            const float e = eps[gi * 3 + c];
            const float pre = fmaf(sd, e, v[c]);
            out[gi * 3 + c] = tanhf(pre) * 0.01f;
            const float t2 = 2.f * pre;
            lp += -0.5f * e * e - als - 2.3052328944f + softplusf(t2) + softplusf(-t2);
        }
        lp = red16(lp);                     // per-16-lane-row sums
        lp += __shfl_xor(lp, 16, 64);       // combine the two rows
        if (t == 0) atomicAdd(out + 8 * NTOK * 3 + b, lp);
    }
}

extern "C" void kernel_launch(void* const* d_in, const int* in_sizes, int n_in,
                              void* d_out, int out_size, void* d_ws, size_t ws_size,
                              hipStream_t stream) {
    const float* kv = (const float*)d_in[0];
    const float* pos = (const float*)d_in[1];
    const float* eps = (const float*)d_in[2];
    float* out = (float*)d_out;
    unsigned short* frag = (unsigned short*)d_ws;   // 8 MiB

    prepass_kernel<<<dim3(1024), 256, 0, stream>>>(kv, frag, out);
    actor_kernel<<<dim3(256), 1024, 0, stream>>>(frag, pos, eps, out);
}

// Round 12
// 89.175 us; speedup vs baseline: 1.2273x; 1.2273x over previous
//
#include <hip/hip_runtime.h>
#include <math.h>

// B=8, N=1024, D=128.  kv[b,n,512] = [k_mu | v_mu | k_sigma | v_sigma]
// 3-kernel plan (transposed GEMM, 32-i x 512-j blocks, V-frag sharing):
//  1) prepass: round fp32 -> bf16 into MFMA-fragment order:
//     frag[side][b][tile16][kc][arr][512 ush], chunk = 64 lanes x 8 bf16.
//     side0 = K (cols 0/256), side1 = V (cols 128/384); arr 0=mu 1=sg.
//     Seeds the 8 log-prob slots of out with LPCONST.
//  2) actor: S^T = V.K^T. Block = 512 thr (8 waves), 32 i (TWO 16-i tiles
//     sharing every V fragment -> V traffic 266->133 MB; R8/R10 show the
//     kernel is bound by V-frag reads at ~7.5 TB/s) x 512 j (jh half).
//     K frags for both tiles resident (64 VGPRs). Grid 512 blocks = 2/CU
//     = 16 waves/CU (same occupancy as R10 -- R11's 256-block/1024-thr
//     version collapsed to VGPR=64 + 54 MB spill). C[row=j][col=i]:
//     lane's col = fixed i per tile, 4 regs = 4 j -> geometric j-sum folds
//     in-register; q-group shuffle; cross-wave LDS combine;
//     partial[jh][b][i][6].
//  3) tail: 128 blocks x 64 thr; sums 2 jh partials, tanh-normal math,
//     per-wave log_prob reduce + atomicAdd.
// NOTE: 512-thread blocks + plain __launch_bounds__(512) is the only
// config that never spilled (VGPR 52-60, R8-R10). Never use the
// min-waves arg (R5) or 1024-thr blocks (R11). No __threadfence (R9).
// Plain bf16 is accuracy-safe: absmax 4096 identical for fp32 /
// split-bf16 / bf16 runs (accumulation-order noise dominates).

#define NTOK 1024
#define LPCONST 14147.0828114f   // -3072*ln(0.01)

typedef __bf16 bf16x8 __attribute__((ext_vector_type(8)));
typedef float f32x4 __attribute__((ext_vector_type(4)));
#define MFMA(a, b, c) __builtin_amdgcn_mfma_f32_16x16x32_bf16(a, b, c, 0, 0, 0)

__device__ __forceinline__ unsigned short to_bf16(float x) {
    return (unsigned short)((__float_as_uint(x) + 0x8000u) >> 16);
}

template <int CTRL>
__device__ __forceinline__ float dpp_add(float v) {
    int y = __builtin_amdgcn_update_dpp(0, __float_as_int(v), CTRL, 0xf, 0xf, true);
    return v + __int_as_float(y);
}
__device__ __forceinline__ float red16(float v) {
    v = dpp_add<0xB1>(v);    // xor1 within quad
    v = dpp_add<0x4E>(v);    // xor2 within quad
    v = dpp_add<0x141>(v);   // row_half_mirror
    v = dpp_add<0x140>(v);   // row_mirror
    return v;
}

__device__ __forceinline__ float softplusf(float z) {
    return z > 20.f ? z : log1pf(expf(z));
}

// ---------------- prepass ----------------
__global__ __launch_bounds__(256) void prepass_kernel(
    const float* __restrict__ kv, unsigned short* __restrict__ frag,
    float* __restrict__ out)
{
    const int t = blockIdx.x * 256 + threadIdx.x;   // 0..262143
    if (t < 8) out[8 * NTOK * 3 + t] = LPCONST;     // seed log-prob slots

    const int lane = t & 63;
    const int kc   = (t >> 6) & 3;
    const int tile = (t >> 8) & 63;
    const int b    = (t >> 14) & 7;
    const int side = t >> 17;

    const int row = tile * 16 + (lane & 15);
    const int kof = kc * 32 + (lane >> 4) * 8;
    const float* gp = kv + ((size_t)b * NTOK + row) * 512 + side * 128 + kof;
    const float4 m0 = *(const float4*)gp;
    const float4 m1 = *(const float4*)(gp + 4);
    const float4 s0 = *(const float4*)(gp + 256);
    const float4 s1 = *(const float4*)(gp + 260);

    unsigned short* cp = frag + (size_t)side * 2097152 +
                         (size_t)(b * 64 + tile) * 4096 + kc * 1024 + lane * 8;
    ushort4 h0, h1;
    h0.x = to_bf16(m0.x); h0.y = to_bf16(m0.y); h0.z = to_bf16(m0.z); h0.w = to_bf16(m0.w);
    h1.x = to_bf16(m1.x); h1.y = to_bf16(m1.y); h1.z = to_bf16(m1.z); h1.w = to_bf16(m1.w);
    *(ushort4*)(cp + 0) = h0; *(ushort4*)(cp + 4) = h1;       // arr0 mu
    h0.x = to_bf16(s0.x); h0.y = to_bf16(s0.y); h0.z = to_bf16(s0.z); h0.w = to_bf16(s0.w);
    h1.x = to_bf16(s1.x); h1.y = to_bf16(s1.y); h1.z = to_bf16(s1.z); h1.w = to_bf16(s1.w);
    *(ushort4*)(cp + 512) = h0; *(ushort4*)(cp + 516) = h1;   // arr1 sg
}

// ---------------- gemm^T + geometry, 32 i x 512 j per block ----------------
__global__ __launch_bounds__(512) void actor_kernel(
    const unsigned short* __restrict__ frag, const float* __restrict__ pos,
    float* __restrict__ partial)
{
    const int t = threadIdx.x;
    const int w = t >> 6;        // wave 0..7
    const int lane = t & 63;
    const int q = lane >> 4;
    const int r16 = lane & 15;
    const int b    = blockIdx.x & 7;
    const int jh   = (blockIdx.x >> 3) & 1;
    const int ithx = blockIdx.x >> 4;        // 0..31
    const int i0 = ithx * 32;

    const unsigned short* fragK = frag;             // side 0
    const unsigned short* fragV = frag + 2097152;   // side 1
    const float* posb = pos + (size_t)b * NTOK * 3;

    __shared__ float spos[NTOK * 3];      // 12 KB
    __shared__ float wacc[8 * 32 * 6];    // 6 KB

    // ---- stage all positions for this batch into LDS (coalesced) ----
    for (int u = t; u < 768; u += 512)
        *(float4*)&spos[u * 4] = *(const float4*)&posb[u * 4];

    // ---- preload K frags for both 16-i tiles: 64 VGPRs ----
    const unsigned short* kp =
        fragK + (size_t)(b * 64 + ithx * 2) * 4096 + lane * 8;
    bf16x8 Km0[4], Ks0[4], Km1[4], Ks1[4];
    #pragma unroll
    for (int kc = 0; kc < 4; ++kc) {
        Km0[kc] = *(const bf16x8*)(kp + kc * 1024);
        Ks0[kc] = *(const bf16x8*)(kp + kc * 1024 + 512);
        Km1[kc] = *(const bf16x8*)(kp + 4096 + kc * 1024);
        Ks1[kc] = *(const bf16x8*)(kp + 4096 + kc * 1024 + 512);
    }

    __syncthreads();

    // lane's i per tile (C column) is fixed
    const float pix0 = spos[(i0 + r16) * 3 + 0];
    const float piy0 = spos[(i0 + r16) * 3 + 1];
    const float piz0 = spos[(i0 + r16) * 3 + 2];
    const float pix1 = spos[(i0 + 16 + r16) * 3 + 0];
    const float piy1 = spos[(i0 + 16 + r16) * 3 + 1];
    const float piz1 = spos[(i0 + 16 + r16) * 3 + 2];

    float am[2][3] = {};   // [tile][c]
    float al[2][3] = {};

    const int jtile0 = jh * 32 + w * 4;   // this wave's first 16-j tile
    const unsigned short* vbase =
        fragV + (size_t)(b * 64 + jtile0) * 4096 + lane * 8;

    #pragma unroll
    for (int jt = 0; jt < 4; ++jt) {
        const unsigned short* vp = vbase + jt * 4096;
        f32x4 accm0 = (f32x4){0.f, 0.f, 0.f, 0.f};
        f32x4 accs0 = (f32x4){0.f, 0.f, 0.f, 0.f};
        f32x4 accm1 = (f32x4){0.f, 0.f, 0.f, 0.f};
        f32x4 accs1 = (f32x4){0.f, 0.f, 0.f, 0.f};
        #pragma unroll
        for (int kc = 0; kc < 4; ++kc) {
            const bf16x8 Vm = *(const bf16x8*)(vp + kc * 1024);
            const bf16x8 Vs = *(const bf16x8*)(vp + kc * 1024 + 512);
            accm0 = MFMA(Vm, Km0[kc], accm0);   // C[row=j][col=i], tile 0
            accs0 = MFMA(Vs, Ks0[kc], accs0);
            accm1 = MFMA(Vm, Km1[kc], accm1);   // tile 1 shares the V frags
            accs1 = MFMA(Vs, Ks1[kc], accs1);
        }
        // ---- fold this tile's 4 j's (rows q*4+reg) into per-i sums ----
        const int jbase = (jtile0 + jt) * 16 + q * 4;
        #pragma unroll
        for (int reg = 0; reg < 4; ++reg) {
            const float* pj = &spos[(jbase + reg) * 3];  // LDS broadcast
            {   // tile 0
                const float dx = pix0 - pj[0];
                const float dy = piy0 - pj[1];
                const float dz = piz0 - pj[2];
                const float d2 = dx * dx + dy * dy + dz * dz;
                const float inv = d2 > 0.f ? rsqrtf(d2) : 0.f;
                const float wm = accm0[reg] * inv;
                const float ws = accs0[reg] * inv;
                am[0][0] = fmaf(dx, wm, am[0][0]);
                am[0][1] = fmaf(dy, wm, am[0][1]);
                am[0][2] = fmaf(dz, wm, am[0][2]);
                al[0][0] = fmaf(dx, ws, al[0][0]);
                al[0][1] = fmaf(dy, ws, al[0][1]);
                al[0][2] = fmaf(dz, ws, al[0][2]);
            }
            {   // tile 1
                const float dx = pix1 - pj[0];
                const float dy = piy1 - pj[1];
                const float dz = piz1 - pj[2];
                const float d2 = dx * dx + dy * dy + dz * dz;
                const float inv = d2 > 0.f ? rsqrtf(d2) : 0.f;
                const float wm = accm1[reg] * inv;
                const float ws = accs1[reg] * inv;
                am[1][0] = fmaf(dx, wm, am[1][0]);
                am[1][1] = fmaf(dy, wm, am[1][1]);
                am[1][2] = fmaf(dz, wm, am[1][2]);
                al[1][0] = fmaf(dx, ws, al[1][0]);
                al[1][1] = fmaf(dy, ws, al[1][1]);
                al[1][2] = fmaf(dz, ws, al[1][2]);
            }
        }
    }

    // ---- reduce over the 4 q-groups (lanes r16, +16, +32, +48) ----
    #pragma unroll
    for (int tile = 0; tile < 2; ++tile)
        #pragma unroll
        for (int c = 0; c < 3; ++c) {
            float vm = am[tile][c], vl = al[tile][c];
            vm += __shfl_xor(vm, 16, 64); vm += __shfl_xor(vm, 32, 64);
            vl += __shfl_xor(vl, 16, 64); vl += __shfl_xor(vl, 32, 64);
            am[tile][c] = vm; al[tile][c] = vl;
        }

    // ---- cross-wave combine via LDS -> partial[jh][b][i][6] ----
    if (lane < 16) {
        #pragma unroll
        for (int tile = 0; tile < 2; ++tile) {
            float* p = wacc + (w * 32 + tile * 16 + r16) * 6;
            p[0] = am[tile][0]; p[1] = am[tile][1]; p[2] = am[tile][2];
            p[3] = al[tile][0]; p[4] = al[tile][1]; p[5] = al[tile][2];
        }
    }
    __syncthreads();
    if (t < 192) {
        float v = 0.f;
        #pragma unroll
        for (int ww = 0; ww < 8; ++ww) v += wacc[ww * 192 + t];
        const int row = t / 6, c = t - row * 6;
        partial[((size_t)((jh * 8 + b) * NTOK) + i0 + row) * 6 + c] = v;
    }
}

// ---------------- tail ----------------
__global__ __launch_bounds__(64) void actor_tail_kernel(
    const float* __restrict__ partial, const float* __restrict__ eps,
    float* __restrict__ out)
{
    const int b = blockIdx.x >> 4;
    const int i = (blockIdx.x & 15) * 64 + threadIdx.x;
    const int gi = b * NTOK + i;

    float am[3], al[3];
    {
        const float* p0 = partial + (((size_t)0 * 8 + b) * NTOK + i) * 6;
        const float* p1 = partial + (((size_t)1 * 8 + b) * NTOK + i) * 6;
        am[0] = p0[0] + p1[0]; am[1] = p0[1] + p1[1]; am[2] = p0[2] + p1[2];
        al[0] = p0[3] + p1[3]; al[1] = p0[4] + p1[4]; al[2] = p0[5] + p1[5];
    }

    float lp = 0.f;
    #pragma unroll
    for (int c = 0; c < 3; ++c) {
        const float als = fminf(fmaxf(al[c], -20.f), 2.f);
        const float sd = expf(als);
        const float e = eps[gi * 3 + c];
        const float pre = fmaf(sd, e, am[c]);
        out[gi * 3 + c] = tanhf(pre) * 0.01f;
        const float t2 = 2.f * pre;
        lp += -0.5f * e * e - als - 2.3052328944f + softplusf(t2) + softplusf(-t2);
    }

    #pragma unroll
    for (int m = 1; m < 64; m <<= 1) lp += __shfl_xor(lp, m, 64);
    if (threadIdx.x == 0) atomicAdd(out + NTOK * 8 * 3 + b, lp);
}

extern "C" void kernel_launch(void* const* d_in, const int* in_sizes, int n_in,
                              void* d_out, int out_size, void* d_ws, size_t ws_size,
                              hipStream_t stream) {
    const float* kv = (const float*)d_in[0];
    const float* pos = (const float*)d_in[1];
    const float* eps = (const float*)d_in[2];
    float* out = (float*)d_out;
    unsigned short* frag = (unsigned short*)d_ws;                 // 8 MiB
    float* partial = (float*)((char*)d_ws + 8388608);             // 384 KiB

    prepass_kernel<<<dim3(1024), 256, 0, stream>>>(kv, frag, out);
    actor_kernel<<<dim3(512), 512, 0, stream>>>(frag, pos, partial);
    actor_tail_kernel<<<dim3(128), 64, 0, stream>>>(partial, eps, out);
}

// Round 13
// 88.054 us; speedup vs baseline: 1.2429x; 1.0127x over previous
//
#include <hip/hip_runtime.h>
#include <math.h>

// B=8, N=1024, D=128.  kv[b,n,512] = [k_mu | v_mu | k_sigma | v_sigma]
// 3-kernel plan (transposed GEMM, 64-i x 256-j blocks, K in LDS):
//  1) prepass: round fp32 -> bf16 into MFMA-fragment order:
//     frag[side][b][tile16][kc][arr][512 ush], chunk = 64 lanes x 8 bf16.
//     side0 = K (cols 0/256), side1 = V (cols 128/384); arr 0=mu 1=sg.
//     Seeds the 8 log-prob slots of out with LPCONST.
//  2) actor: S^T = V.K^T. Block = 512 thr (8 waves), 64 i (FOUR 16-i tiles
//     share every V fragment -> V traffic 266(R10)->133(R12)->64 MB) x
//     256 j (jh quarter). K for the 4 tiles staged in LDS (32 KB; VGPR-
//     resident K for 4 tiles = 128 regs would halve occupancy per the
//     vgpr={64,128,256} wave-step). Grid 512 blocks = 2/CU = 16 waves/CU
//     (R8-R12: the occupancy that works). C[row=j][col=i]: lane's col =
//     fixed i per tile, 4 regs = 4 j -> geometric j-sum folds in-register;
//     q-group shuffle; cross-wave LDS combine; partial[jh][b][i][6].
//  3) tail: 128 blocks x 64 thr; sums 4 jh partials, tanh-normal math,
//     per-wave log_prob reduce + atomicAdd.
// NOTE: 512-thread blocks + plain __launch_bounds__(512) is the only
// config that never spilled (VGPR 52-60, R8-R12). Never use the
// min-waves arg (R5: VGPR=64 clamp + 100MB spill) or 1024-thr blocks
// (R11: same). No __threadfence / cross-block merge (R9: wbl2 storms).
// Plain bf16 is accuracy-safe: absmax 4096 identical for fp32 /
// split-bf16 / bf16 runs (accumulation-order noise dominates).

#define NTOK 1024
#define LPCONST 14147.0828114f   // -3072*ln(0.01)

typedef __bf16 bf16x8 __attribute__((ext_vector_type(8)));
typedef float f32x4 __attribute__((ext_vector_type(4)));
#define MFMA(a, b, c) __builtin_amdgcn_mfma_f32_16x16x32_bf16(a, b, c, 0, 0, 0)

__device__ __forceinline__ unsigned short to_bf16(float x) {
    return (unsigned short)((__float_as_uint(x) + 0x8000u) >> 16);
}

__device__ __forceinline__ float softplusf(float z) {
    return z > 20.f ? z : log1pf(expf(z));
}

// ---------------- prepass ----------------
__global__ __launch_bounds__(256) void prepass_kernel(
    const float* __restrict__ kv, unsigned short* __restrict__ frag,
    float* __restrict__ out)
{
    const int t = blockIdx.x * 256 + threadIdx.x;   // 0..262143
    if (t < 8) out[8 * NTOK * 3 + t] = LPCONST;     // seed log-prob slots

    const int lane = t & 63;
    const int kc   = (t >> 6) & 3;
    const int tile = (t >> 8) & 63;
    const int b    = (t >> 14) & 7;
    const int side = t >> 17;

    const int row = tile * 16 + (lane & 15);
    const int kof = kc * 32 + (lane >> 4) * 8;
    const float* gp = kv + ((size_t)b * NTOK + row) * 512 + side * 128 + kof;
    const float4 m0 = *(const float4*)gp;
    const float4 m1 = *(const float4*)(gp + 4);
    const float4 s0 = *(const float4*)(gp + 256);
    const float4 s1 = *(const float4*)(gp + 260);

    unsigned short* cp = frag + (size_t)side * 2097152 +
                         (size_t)(b * 64 + tile) * 4096 + kc * 1024 + lane * 8;
    ushort4 h0, h1;
    h0.x = to_bf16(m0.x); h0.y = to_bf16(m0.y); h0.z = to_bf16(m0.z); h0.w = to_bf16(m0.w);
    h1.x = to_bf16(m1.x); h1.y = to_bf16(m1.y); h1.z = to_bf16(m1.z); h1.w = to_bf16(m1.w);
    *(ushort4*)(cp + 0) = h0; *(ushort4*)(cp + 4) = h1;       // arr0 mu
    h0.x = to_bf16(s0.x); h0.y = to_bf16(s0.y); h0.z = to_bf16(s0.z); h0.w = to_bf16(s0.w);
    h1.x = to_bf16(s1.x); h1.y = to_bf16(s1.y); h1.z = to_bf16(s1.z); h1.w = to_bf16(s1.w);
    *(ushort4*)(cp + 512) = h0; *(ushort4*)(cp + 516) = h1;   // arr1 sg
}

// ---------------- gemm^T + geometry, 64 i x 256 j per block ----------------
__global__ __launch_bounds__(512) void actor_kernel(
    const unsigned short* __restrict__ frag, const float* __restrict__ pos,
    float* __restrict__ partial)
{
    const int t = threadIdx.x;
    const int w = t >> 6;        // wave 0..7
    const int lane = t & 63;
    const int q = lane >> 4;
    const int r16 = lane & 15;
    const int b   = blockIdx.x & 7;
    const int jh  = (blockIdx.x >> 3) & 3;   // j quarter
    const int ibx = blockIdx.x >> 5;         // 0..15
    const int i0 = ibx * 64;

    const unsigned short* fragK = frag;             // side 0
    const unsigned short* fragV = frag + 2097152;   // side 1
    const float* posb = pos + (size_t)b * NTOK * 3;

    __shared__ unsigned short sK[16384];  // 32 KB: 4 K tiles in frag layout
    __shared__ float spos[NTOK * 3];      // 12 KB
    __shared__ float wacc[8 * 64 * 6];    // 12 KB

    // ---- stage K (4 tiles, 32 KB) + positions into LDS (coalesced) ----
    {
        const unsigned short* kg =
            fragK + (size_t)(b * 64 + ibx * 4) * 4096 + t * 32;
        #pragma unroll
        for (int r = 0; r < 4; ++r)
            *(ushort4*)&sK[t * 32 + r * 4] = *(const ushort4*)(kg + r * 4);
        const unsigned short* kg2 = kg + 16;
        #pragma unroll
        for (int r = 0; r < 4; ++r)
            *(ushort4*)&sK[t * 32 + 16 + r * 4] = *(const ushort4*)(kg2 + r * 4);
    }
    for (int u = t; u < 768; u += 512)
        *(float4*)&spos[u * 4] = *(const float4*)&posb[u * 4];
    __syncthreads();

    // lane's i per tile (C column) is fixed
    float pix[4], piy[4], piz[4];
    #pragma unroll
    for (int tile = 0; tile < 4; ++tile) {
        pix[tile] = spos[(i0 + tile * 16 + r16) * 3 + 0];
        piy[tile] = spos[(i0 + tile * 16 + r16) * 3 + 1];
        piz[tile] = spos[(i0 + tile * 16 + r16) * 3 + 2];
    }

    float am[4][3] = {};   // [tile][c]
    float al[4][3] = {};

    const int jtile0 = jh * 16 + w * 2;   // this wave's first 16-j tile
    const unsigned short* vbase =
        fragV + (size_t)(b * 64 + jtile0) * 4096 + lane * 8;
    const int klofs = lane * 8;

    #pragma unroll
    for (int jt = 0; jt < 2; ++jt) {
        const unsigned short* vp = vbase + jt * 4096;
        f32x4 accm[4], accs[4];
        #pragma unroll
        for (int tile = 0; tile < 4; ++tile) {
            accm[tile] = (f32x4){0.f, 0.f, 0.f, 0.f};
            accs[tile] = (f32x4){0.f, 0.f, 0.f, 0.f};
        }
        #pragma unroll
        for (int kc = 0; kc < 4; ++kc) {
            const bf16x8 Vm = *(const bf16x8*)(vp + kc * 1024);
            const bf16x8 Vs = *(const bf16x8*)(vp + kc * 1024 + 512);
            #pragma unroll
            for (int tile = 0; tile < 4; ++tile) {
                const bf16x8 Km = *(const bf16x8*)&sK[tile * 4096 + kc * 1024 + klofs];
                const bf16x8 Ks = *(const bf16x8*)&sK[tile * 4096 + kc * 1024 + 512 + klofs];
                accm[tile] = MFMA(Vm, Km, accm[tile]);   // C[row=j][col=i]
                accs[tile] = MFMA(Vs, Ks, accs[tile]);
            }
        }
        // ---- fold this tile's 4 j's (rows q*4+reg) into per-i sums ----
        const int jbase = (jtile0 + jt) * 16 + q * 4;
        #pragma unroll
        for (int reg = 0; reg < 4; ++reg) {
            const float* pj = &spos[(jbase + reg) * 3];  // LDS broadcast
            const float pjx = pj[0], pjy = pj[1], pjz = pj[2];
            #pragma unroll
            for (int tile = 0; tile < 4; ++tile) {
                const float dx = pix[tile] - pjx;
                const float dy = piy[tile] - pjy;
                const float dz = piz[tile] - pjz;
                const float d2 = dx * dx + dy * dy + dz * dz;
                const float inv = d2 > 0.f ? rsqrtf(d2) : 0.f;  // i==j -> 0
                const float wm = accm[tile][reg] * inv;
                const float ws = accs[tile][reg] * inv;
                am[tile][0] = fmaf(dx, wm, am[tile][0]);
                am[tile][1] = fmaf(dy, wm, am[tile][1]);
                am[tile][2] = fmaf(dz, wm, am[tile][2]);
                al[tile][0] = fmaf(dx, ws, al[tile][0]);
                al[tile][1] = fmaf(dy, ws, al[tile][1]);
                al[tile][2] = fmaf(dz, ws, al[tile][2]);
            }
        }
    }

    // ---- reduce over the 4 q-groups (lanes r16, +16, +32, +48) ----
    #pragma unroll
    for (int tile = 0; tile < 4; ++tile)
        #pragma unroll
        for (int c = 0; c < 3; ++c) {
            float vm = am[tile][c], vl = al[tile][c];
            vm += __shfl_xor(vm, 16, 64); vm += __shfl_xor(vm, 32, 64);
            vl += __shfl_xor(vl, 16, 64); vl += __shfl_xor(vl, 32, 64);
            am[tile][c] = vm; al[tile][c] = vl;
        }

    // ---- cross-wave combine via LDS -> partial[jh][b][i][6] ----
    if (lane < 16) {
        #pragma unroll
        for (int tile = 0; tile < 4; ++tile) {
            float* p = wacc + (w * 64 + tile * 16 + r16) * 6;
            p[0] = am[tile][0]; p[1] = am[tile][1]; p[2] = am[tile][2];
            p[3] = al[tile][0]; p[4] = al[tile][1]; p[5] = al[tile][2];
        }
    }
    __syncthreads();
    if (t < 384) {
        float v = 0.f;
        #pragma unroll
        for (int ww = 0; ww < 8; ++ww) v += wacc[ww * 384 + t];
        const int row = t / 6, c = t - row * 6;
        partial[((size_t)((jh * 8 + b) * NTOK) + i0 + row) * 6 + c] = v;
    }
}

// ---------------- tail ----------------
__global__ __launch_bounds__(64) void actor_tail_kernel(
    const float* __restrict__ partial, const float* __restrict__ eps,
    float* __restrict__ out)
{
    const int b = blockIdx.x >> 4;
    const int i = (blockIdx.x & 15) * 64 + threadIdx.x;
    const int gi = b * NTOK + i;

    float am[3] = {}, al[3] = {};
    #pragma unroll
    for (int jh = 0; jh < 4; ++jh) {
        const float* p = partial + (((size_t)jh * 8 + b) * NTOK + i) * 6;
        const float2 v0 = *(const float2*)(p);
        const float2 v1 = *(const float2*)(p + 2);
        const float2 v2 = *(const float2*)(p + 4);
        am[0] += v0.x; am[1] += v0.y; am[2] += v1.x;
        al[0] += v1.y; al[1] += v2.x; al[2] += v2.y;
    }

    float lp = 0.f;
    #pragma unroll
    for (int c = 0; c < 3; ++c) {
        const float als = fminf(fmaxf(al[c], -20.f), 2.f);
        const float sd = expf(als);
        const float e = eps[gi * 3 + c];
        const float pre = fmaf(sd, e, am[c]);
        out[gi * 3 + c] = tanhf(pre) * 0.01f;
        const float t2 = 2.f * pre;
        lp += -0.5f * e * e - als - 2.3052328944f + softplusf(t2) + softplusf(-t2);
    }

    #pragma unroll
    for (int m = 1; m < 64; m <<= 1) lp += __shfl_xor(lp, m, 64);
    if (threadIdx.x == 0) atomicAdd(out + NTOK * 8 * 3 + b, lp);
}

extern "C" void kernel_launch(void* const* d_in, const int* in_sizes, int n_in,
                              void* d_out, int out_size, void* d_ws, size_t ws_size,
                              hipStream_t stream) {
    const float* kv = (const float*)d_in[0];
    const float* pos = (const float*)d_in[1];
    const float* eps = (const float*)d_in[2];
    float* out = (float*)d_out;
    unsigned short* frag = (unsigned short*)d_ws;                 // 8 MiB
    float* partial = (float*)((char*)d_ws + 8388608);             // 768 KiB

    prepass_kernel<<<dim3(1024), 256, 0, stream>>>(kv, frag, out);
    actor_kernel<<<dim3(512), 512, 0, stream>>>(frag, pos, partial);
    actor_tail_kernel<<<dim3(128), 64, 0, stream>>>(partial, eps, out);
}